// Round 13
// baseline (58.741 us; speedup 1.0000x reference)
//
#include <hip/hip_runtime.h>
#include <math.h>

#define SRf 48000.0f
#define CSOUND 343.0f
#define RIR_LEN 24000
#define TAPS 81
#define HALFT 40
#define NB 8
#define NM 21                 // per-axis entries with order <= 10
#define NTRIP (NM * NM * NM)  // 9261 candidate triples
#define NSL 16                // image-slices per batch -> 128 paint blocks
#define BLOCK 1024
#define CAPS 256              // per-slice keeper capacity (mean ~98)

// 0.9^q for q = 0..10
__device__ __constant__ float c_beta[11] = {
    1.0f, 0.9f, 0.81f, 0.729f, 0.6561f, 0.59049f, 0.531441f,
    0.4782969f, 0.43046721f, 0.387420489f, 0.3486784401f};

// Per-axis image table restricted to order <= 10 (pure arithmetic):
//   m in [0,10]:  p=0, n=m-5  -> sign=+1, off=2n, order=2|n|
//   m in [11,20]: p=1, n=m-15 -> sign=-1, off=2n, order=|n-1|+|n|
__device__ __forceinline__ void axis_entry(int m, float& sgn, float& off, int& ord) {
    if (m < 11) {
        int n = m - 5;
        sgn = 1.0f;
        off = 2.0f * (float)n;
        ord = 2 * abs(n);
    } else {
        int n = m - 15;
        sgn = -1.0f;
        off = 2.0f * (float)n;
        ord = abs(n - 1) + abs(n);
    }
}

// node 1 (tiny): zero the 8 ticket counters + compute the 8 origin outputs.
__global__ __launch_bounds__(64) void k_zero(const float* __restrict__ x,
                                             int* __restrict__ cnt,
                                             float* __restrict__ out) {
    int t = threadIdx.x;
    if (t < NB) {
        cnt[t] = 0;
        const float* xb = x + t * 9;
        float r0 = xb[0] * 10.0f, r1 = xb[1] * 10.0f, r2 = xb[2] * 10.0f;
        float d0 = (xb[3] - xb[6]) * r0;
        float d1 = (xb[4] - xb[7]) * r1;
        float d2 = (xb[5] - xb[8]) * r2;
        float dist = sqrtf(d0 * d0 + d1 * d1 + d2 * d2);
        out[NB * RIR_LEN + t] = 40.0f + SRf * dist / CSOUND;
    }
}

// node 2: paint partial RIR (windowed) + decoupled last-block-per-batch reduce.
__global__ __launch_bounds__(BLOCK) void k_fused(const float* __restrict__ x,
                                                 float* __restrict__ ws,
                                                 int2* __restrict__ hdr,
                                                 int* __restrict__ cnt,
                                                 float* __restrict__ out) {
    __shared__ __align__(16) float s_tile[RIR_LEN];  // 96 KB (window-used)
    __shared__ float4 s_e[CAPS];  // {amp, frac, amp*sin(pi*frac)/pi, i0}
    __shared__ int s_cnt, s_lo, s_hi, s_old;

    const float PIF = 3.14159265358979323846f;
    const int b = blockIdx.x >> 4;          // / NSL
    const int sl = blockIdx.x & (NSL - 1);
    const int tid = threadIdx.x;

    const float* xb = x + b * 9;
    const float r0 = xb[0] * 10.0f, r1 = xb[1] * 10.0f, r2 = xb[2] * 10.0f;
    const float m0 = xb[3] * r0, m1 = xb[4] * r1, m2 = xb[5] * r2;
    const float s0 = xb[6] * r0, s1 = xb[7] * r1, s2 = xb[8] * r2;

    if (tid == 0) { s_cnt = 0; s_lo = RIR_LEN; s_hi = 0; }
    __syncthreads();

    // ---- phase A: register-only scan of residue class (one candidate/thread)
    {
        int r = sl + tid * NSL;
        if (r < NTRIP) {
            int mi = r / (NM * NM);
            int rem = r - mi * (NM * NM);
            int mj = rem / NM;
            int mk = rem - mj * NM;

            float si, oi_; int qi; axis_entry(mi, si, oi_, qi);
            float sj, oj_; int qj; axis_entry(mj, sj, oj_, qj);
            float sk, ok_; int qk; axis_entry(mk, sk, ok_, qk);
            int q = qi + qj + qk;
            if (q <= 10) {
                float dx = si * s0 + oi_ * r0 - m0;
                float dy = sj * s1 + oj_ * r1 - m1;
                float dz = sk * s2 + ok_ * r2 - m2;
                float dist = sqrtf(dx * dx + dy * dy + dz * dz);

                float tau = SRf * dist / CSOUND;
                float i0f = floorf(tau);
                int i0 = (int)i0f;
                if (i0 + HALFT + 1 < RIR_LEN) {  // at least one in-range tap
                    float fr = tau - i0f;
                    float amp = c_beta[q] / (4.0f * PIF * dist);
                    int slot = atomicAdd(&s_cnt, 1);
                    float4 e;
                    e.x = amp;
                    e.y = fr;
                    e.z = amp * __sinf(PIF * fr) * (1.0f / PIF);
                    e.w = __int_as_float(i0);
                    s_e[slot] = e;
                    atomicMin(&s_lo, i0 + HALFT + 1);
                    atomicMax(&s_hi, min(i0 + HALFT + TAPS, RIR_LEN));
                }
            }
        }
    }
    __syncthreads();

    const int lo4 = s_lo & ~3;
    const int hi4 = (s_hi + 3) & ~3;  // <= RIR_LEN
    if (tid == 0) hdr[blockIdx.x] = make_int2(lo4, hi4);

    if (lo4 < hi4) {
        // zero only the window
        for (int j = lo4 + tid * 4; j < hi4; j += BLOCK * 4)
            *(float4*)&s_tile[j] = make_float4(0.f, 0.f, 0.f, 0.f);
        __syncthreads();

        // ---- phase B: flattened (image, tap) paint; tap ki=0 contributes 0
        const int n = s_cnt;
        const int total = n * (TAPS - 1);
        for (int w = tid; w < total; w += BLOCK) {
            int img = w / (TAPS - 1);
            int ki = w - img * (TAPS - 1) + 1;  // 1..80
            float4 e = s_e[img];
            int idx = __float_as_int(e.w) + HALFT + ki;
            if (idx >= RIR_LEN) continue;

            float tt = (float)(ki - HALFT) - e.y;  // in (-40, 40]
            float win = 0.5f * (1.0f + __cosf(PIF * (1.0f / 41.0f) * tt));
            float v = ((ki & 1) ? e.z : -e.z) * __builtin_amdgcn_rcpf(tt);
            v = (tt == 0.0f) ? e.x : v;  // exact-integer delay
            atomicAdd(&s_tile[idx], v * win);
        }
        __syncthreads();

        // ---- phase C: stream only the window to workspace (coalesced float4)
        float* wb = ws + (size_t)blockIdx.x * RIR_LEN;
        for (int j = lo4 + tid * 4; j < hi4; j += BLOCK * 4)
            *(float4*)&wb[j] = *(const float4*)&s_tile[j];
    }
    __syncthreads();

    // ---- release + ticket: only the LAST paint block of batch b reduces.
    if (tid == 0) {
        __threadfence();                   // publish window + hdr (device scope)
        s_old = atomicAdd(&cnt[b], 1);     // device-scope RMW, totally ordered
    }
    __syncthreads();
    if (s_old != NSL - 1) return;

    // ---- phase D (last block only): reduce 16 windowed partials -> out[b]
    __threadfence();  // acquire side
    int2 w[NSL];
    #pragma unroll
    for (int s = 0; s < NSL; ++s) w[s] = hdr[b * NSL + s];
    const float* base = ws + (size_t)b * NSL * RIR_LEN;
    for (int j4 = tid * 4; j4 < RIR_LEN; j4 += BLOCK * 4) {
        float4 acc = make_float4(0.f, 0.f, 0.f, 0.f);
        #pragma unroll
        for (int s = 0; s < NSL; ++s) {
            if (j4 >= w[s].x && j4 < w[s].y) {
                float4 v = *(const float4*)(base + (size_t)s * RIR_LEN + j4);
                acc.x += v.x; acc.y += v.y; acc.z += v.z; acc.w += v.w;
            }
        }
        *(float4*)(out + (size_t)b * RIR_LEN + j4) = acc;
    }
}

extern "C" void kernel_launch(void* const* d_in, const int* in_sizes, int n_in,
                              void* d_out, int out_size, void* d_ws, size_t ws_size,
                              hipStream_t stream) {
    const float* x = (const float*)d_in[0];
    float* out = (float*)d_out;

    float* ws = (float*)d_ws;  // partials: 128 * 24000 floats = 12.29 MB
    int2* hdr = (int2*)((char*)d_ws + (size_t)NB * NSL * RIR_LEN * sizeof(float));
    int* cnt = (int*)(hdr + NB * NSL);

    k_zero<<<1, 64, 0, stream>>>(x, cnt, out);
    k_fused<<<NB * NSL, BLOCK, 0, stream>>>(x, ws, hdr, cnt, out);
}

// Round 14
// 42.558 us; speedup vs baseline: 1.3802x; 1.3802x over previous
//
#include <hip/hip_runtime.h>
#include <math.h>

#define SRf 48000.0f
#define CSOUND 343.0f
#define RIR_LEN 24000
#define TAPS 81
#define HALFT 40
#define NB 8
#define NM 21                 // per-axis entries with order <= 10
#define NTRIP (NM * NM * NM)  // 9261 candidate triples
#define NSL 16                // image-slices per batch (r % NSL) -> 128 balanced blocks
#define BLOCK 1024
#define CAPS 256              // per-slice keeper capacity (mean ~98)

// 0.9^q for q = 0..10
__device__ __constant__ float c_beta[11] = {
    1.0f, 0.9f, 0.81f, 0.729f, 0.6561f, 0.59049f, 0.531441f,
    0.4782969f, 0.43046721f, 0.387420489f, 0.3486784401f};

// Per-axis image table restricted to order <= 10 (pure arithmetic):
//   m in [0,10]:  p=0, n=m-5  -> sign=+1, off=2n, order=2|n|
//   m in [11,20]: p=1, n=m-15 -> sign=-1, off=2n, order=|n-1|+|n|
__device__ __forceinline__ void axis_entry(int m, float& sgn, float& off, int& ord) {
    if (m < 11) {
        int n = m - 5;
        sgn = 1.0f;
        off = 2.0f * (float)n;
        ord = 2 * abs(n);
    } else {
        int n = m - 15;
        sgn = -1.0f;
        off = 2.0f * (float)n;
        ord = abs(n - 1) + abs(n);
    }
}

// kernel 1: block = (batch, slice). Scan residue class r%NSL==sl register-only,
// compact keepers to LDS, paint private 96 KB LDS RIR, stream to ws.
// Pure function of x -> ws slice: duplicating this node is bit-identical.
__global__ __launch_bounds__(BLOCK) void k_paint(const float* __restrict__ x,
                                                 float* __restrict__ ws) {
    __shared__ __align__(16) float s_tile[RIR_LEN];  // 96 KB private partial RIR
    __shared__ float4 s_e[CAPS];  // {amp, frac, amp*sin(pi*frac)/pi, i0}
    __shared__ int s_cnt;

    const float PIF = 3.14159265358979323846f;
    const int b = blockIdx.x >> 4;          // / NSL
    const int sl = blockIdx.x & (NSL - 1);
    const int tid = threadIdx.x;

    const float* xb = x + b * 9;
    const float r0 = xb[0] * 10.0f, r1 = xb[1] * 10.0f, r2 = xb[2] * 10.0f;
    const float m0 = xb[3] * r0, m1 = xb[4] * r1, m2 = xb[5] * r2;
    const float s0 = xb[6] * r0, s1 = xb[7] * r1, s2 = xb[8] * r2;

    if (tid == 0) s_cnt = 0;
    for (int j = tid * 4; j < RIR_LEN; j += BLOCK * 4)
        *(float4*)&s_tile[j] = make_float4(0.f, 0.f, 0.f, 0.f);
    __syncthreads();

    // ---- phase A: register-only scan of residue class (one candidate/thread)
    {
        int r = sl + tid * NSL;
        if (r < NTRIP) {
            int mi = r / (NM * NM);
            int rem = r - mi * (NM * NM);
            int mj = rem / NM;
            int mk = rem - mj * NM;

            float si, oi_; int qi; axis_entry(mi, si, oi_, qi);
            float sj, oj_; int qj; axis_entry(mj, sj, oj_, qj);
            float sk, ok_; int qk; axis_entry(mk, sk, ok_, qk);
            int q = qi + qj + qk;
            if (q <= 10) {
                float dx = si * s0 + oi_ * r0 - m0;
                float dy = sj * s1 + oj_ * r1 - m1;
                float dz = sk * s2 + ok_ * r2 - m2;
                float dist = sqrtf(dx * dx + dy * dy + dz * dz);

                float tau = SRf * dist / CSOUND;
                float i0f = floorf(tau);
                int i0 = (int)i0f;
                if (i0 + HALFT + 1 < RIR_LEN) {  // at least one in-range tap
                    float fr = tau - i0f;
                    float amp = c_beta[q] / (4.0f * PIF * dist);
                    int slot = atomicAdd(&s_cnt, 1);
                    float4 e;
                    e.x = amp;
                    e.y = fr;
                    e.z = amp * __sinf(PIF * fr) * (1.0f / PIF);
                    e.w = __int_as_float(i0);
                    s_e[slot] = e;
                }
            }
        }
    }
    __syncthreads();

    // ---- phase B: flattened (image, tap) paint. Tap ki=0 contributes exactly 0
    // (|t|>40 unless frac==0, then sinc(-40)=0), so loop ki=1..80.
    const int n = s_cnt;
    const int total = n * (TAPS - 1);
    for (int w = tid; w < total; w += BLOCK) {
        int img = w / (TAPS - 1);
        int ki = w - img * (TAPS - 1) + 1;  // 1..80
        float4 e = s_e[img];
        int idx = __float_as_int(e.w) + HALFT + ki;
        if (idx >= RIR_LEN) continue;

        float tt = (float)(ki - HALFT) - e.y;  // in (-40, 40]
        float win = 0.5f * (1.0f + __cosf(PIF * (1.0f / 41.0f) * tt));
        float v = ((ki & 1) ? e.z : -e.z) * __builtin_amdgcn_rcpf(tt);
        v = (tt == 0.0f) ? e.x : v;  // exact-integer delay
        atomicAdd(&s_tile[idx], v * win);
    }
    __syncthreads();

    // ---- phase C: stream partial RIR to workspace (coalesced float4)
    float* wb = ws + (size_t)(b * NSL + sl) * RIR_LEN;
    for (int j = tid * 4; j < RIR_LEN; j += BLOCK * 4)
        *(float4*)&wb[j] = *(const float4*)&s_tile[j];
}

// kernel 2: sum the NSL partials per batch -> out; fold in the 8 origins.
__global__ __launch_bounds__(256) void k_reduce(const float* __restrict__ x,
                                                const float* __restrict__ ws,
                                                float* __restrict__ out) {
    int t4 = (blockIdx.x * 256 + threadIdx.x) * 4;
    if (t4 < NB * RIR_LEN) {
        int b = t4 / RIR_LEN;
        int j = t4 - b * RIR_LEN;
        const float* base = ws + (size_t)b * NSL * RIR_LEN + j;
        float4 acc = *(const float4*)base;
        #pragma unroll
        for (int s = 1; s < NSL; ++s) {
            float4 v = *(const float4*)(base + (size_t)s * RIR_LEN);
            acc.x += v.x; acc.y += v.y; acc.z += v.z; acc.w += v.w;
        }
        *(float4*)(out + t4) = acc;
    }
    if (blockIdx.x == 0 && threadIdx.x < NB) {
        const float* xb = x + threadIdx.x * 9;
        float r0 = xb[0] * 10.0f, r1 = xb[1] * 10.0f, r2 = xb[2] * 10.0f;
        float d0 = (xb[3] - xb[6]) * r0;
        float d1 = (xb[4] - xb[7]) * r1;
        float d2 = (xb[5] - xb[8]) * r2;
        float dist = sqrtf(d0 * d0 + d1 * d1 + d2 * d2);
        out[NB * RIR_LEN + threadIdx.x] = 40.0f + SRf * dist / CSOUND;
    }
}

extern "C" void kernel_launch(void* const* d_in, const int* in_sizes, int n_in,
                              void* d_out, int out_size, void* d_ws, size_t ws_size,
                              hipStream_t stream) {
    const float* x = (const float*)d_in[0];
    float* out = (float*)d_out;
    float* ws = (float*)d_ws;  // NB*NSL*RIR_LEN floats = 12.3 MB

    // --- A/B probe: k_paint dispatched TWICE (pure x->ws function, idempotent).
    // Marginal bench delta vs R10 (26.4us) = P(paint) + ~1.5us node overhead.
    k_paint<<<NB * NSL, BLOCK, 0, stream>>>(x, ws);
    k_paint<<<NB * NSL, BLOCK, 0, stream>>>(x, ws);
    int rblocks = (NB * RIR_LEN / 4 + 255) / 256;  // 188
    k_reduce<<<rblocks, 256, 0, stream>>>(x, ws, out);
}

// Round 15
// 24.045 us; speedup vs baseline: 2.4429x; 1.7699x over previous
//
#include <hip/hip_runtime.h>
#include <math.h>

#define SRf 48000.0f
#define CSOUND 343.0f
#define RIR_LEN 24000
#define TAPS 81
#define HALFT 40
#define NB 8
#define NM 21                 // per-axis entries with order <= 10
#define NTRIP (NM * NM * NM)  // 9261 candidate triples
#define NSL 16                // image-slices per batch
#define NH 2                  // halves of the RIR per slice
#define HLEN (RIR_LEN / NH)   // 12000
#define BLOCK 1024
#define CAPS 256              // per-(slice,half) keeper capacity (mean ~54)

// 0.9^q for q = 0..10
__device__ __constant__ float c_beta[11] = {
    1.0f, 0.9f, 0.81f, 0.729f, 0.6561f, 0.59049f, 0.531441f,
    0.4782969f, 0.43046721f, 0.387420489f, 0.3486784401f};

// Per-axis image table restricted to order <= 10 (pure arithmetic):
//   m in [0,10]:  p=0, n=m-5  -> sign=+1, off=2n, order=2|n|
//   m in [11,20]: p=1, n=m-15 -> sign=-1, off=2n, order=|n-1|+|n|
__device__ __forceinline__ void axis_entry(int m, float& sgn, float& off, int& ord) {
    if (m < 11) {
        int n = m - 5;
        sgn = 1.0f;
        off = 2.0f * (float)n;
        ord = 2 * abs(n);
    } else {
        int n = m - 15;
        sgn = -1.0f;
        off = 2.0f * (float)n;
        ord = abs(n - 1) + abs(n);
    }
}

// kernel 1: block = (batch, slice, half). Scan residue class register-only,
// keep images whose 81-tap window intersects this half, paint a private
// 48 KB LDS half-RIR, stream it to ws. 256 blocks -> 1 block/CU chip-wide;
// per-CU critical path (zero + paint + writeout) is HALF of R10's.
__global__ __launch_bounds__(BLOCK) void k_paint(const float* __restrict__ x,
                                                 float* __restrict__ ws) {
    __shared__ __align__(16) float s_tile[HLEN];  // 48 KB private half-RIR
    __shared__ float4 s_e[CAPS];  // {amp, frac, amp*sin(pi*frac)/pi, i0}
    __shared__ int s_cnt;

    const float PIF = 3.14159265358979323846f;
    const int b = blockIdx.x >> 5;          // / (NSL*NH)
    const int sl = (blockIdx.x >> 1) & (NSL - 1);
    const int h = blockIdx.x & 1;
    const int H0 = h * HLEN;
    const int tid = threadIdx.x;

    const float* xb = x + b * 9;
    const float r0 = xb[0] * 10.0f, r1 = xb[1] * 10.0f, r2 = xb[2] * 10.0f;
    const float m0 = xb[3] * r0, m1 = xb[4] * r1, m2 = xb[5] * r2;
    const float s0 = xb[6] * r0, s1 = xb[7] * r1, s2 = xb[8] * r2;

    if (tid == 0) s_cnt = 0;
    for (int j = tid * 4; j < HLEN; j += BLOCK * 4)
        *(float4*)&s_tile[j] = make_float4(0.f, 0.f, 0.f, 0.f);
    __syncthreads();

    // ---- phase A: register-only scan of residue class (one candidate/thread)
    {
        int r = sl + tid * NSL;
        if (r < NTRIP) {
            int mi = r / (NM * NM);
            int rem = r - mi * (NM * NM);
            int mj = rem / NM;
            int mk = rem - mj * NM;

            float si, oi_; int qi; axis_entry(mi, si, oi_, qi);
            float sj, oj_; int qj; axis_entry(mj, sj, oj_, qj);
            float sk, ok_; int qk; axis_entry(mk, sk, ok_, qk);
            int q = qi + qj + qk;
            if (q <= 10) {
                float dx = si * s0 + oi_ * r0 - m0;
                float dy = sj * s1 + oj_ * r1 - m1;
                float dz = sk * s2 + ok_ * r2 - m2;
                float dist = sqrtf(dx * dx + dy * dy + dz * dz);

                float tau = SRf * dist / CSOUND;
                float i0f = floorf(tau);
                int i0 = (int)i0f;
                // in-range taps are idx in [i0+41, i0+120]; intersect [H0, H0+HLEN)?
                if (i0 + HALFT + TAPS - 1 >= H0 && i0 + HALFT + 1 < H0 + HLEN) {
                    float fr = tau - i0f;
                    float amp = c_beta[q] / (4.0f * PIF * dist);
                    int slot = atomicAdd(&s_cnt, 1);
                    float4 e;
                    e.x = amp;
                    e.y = fr;
                    e.z = amp * __sinf(PIF * fr) * (1.0f / PIF);
                    e.w = __int_as_float(i0);
                    s_e[slot] = e;
                }
            }
        }
    }
    __syncthreads();

    // ---- phase B: flattened (image, tap) paint into the half tile.
    // Tap ki=0 contributes exactly 0 (|t|>40 unless frac==0, then sinc(-40)=0).
    const int n = s_cnt;
    const int total = n * (TAPS - 1);
    for (int w = tid; w < total; w += BLOCK) {
        int img = w / (TAPS - 1);
        int ki = w - img * (TAPS - 1) + 1;  // 1..80
        float4 e = s_e[img];
        int idx = __float_as_int(e.w) + HALFT + ki - H0;
        if (idx < 0 || idx >= HLEN) continue;

        float tt = (float)(ki - HALFT) - e.y;  // in (-40, 40]
        float win = 0.5f * (1.0f + __cosf(PIF * (1.0f / 41.0f) * tt));
        float v = ((ki & 1) ? e.z : -e.z) * __builtin_amdgcn_rcpf(tt);
        v = (tt == 0.0f) ? e.x : v;  // exact-integer delay
        atomicAdd(&s_tile[idx], v * win);
    }
    __syncthreads();

    // ---- phase C: stream the half tile to workspace (coalesced float4)
    float* wb = ws + (size_t)blockIdx.x * HLEN;  // [b][sl][h] contiguous
    for (int j = tid * 4; j < HLEN; j += BLOCK * 4)
        *(float4*)&wb[j] = *(const float4*)&s_tile[j];
}

// kernel 2: sum the NSL partials per batch (half-aware) -> out; plus origins.
__global__ __launch_bounds__(256) void k_reduce(const float* __restrict__ x,
                                                const float* __restrict__ ws,
                                                float* __restrict__ out) {
    int t4 = (blockIdx.x * 256 + threadIdx.x) * 4;
    if (t4 < NB * RIR_LEN) {
        int b = t4 / RIR_LEN;
        int j = t4 - b * RIR_LEN;
        int h = j / HLEN;
        int jh = j - h * HLEN;
        const float* base = ws + ((size_t)(b * NSL * NH + h) * HLEN) + jh;
        float4 acc = *(const float4*)base;
        #pragma unroll
        for (int s = 1; s < NSL; ++s) {
            float4 v = *(const float4*)(base + (size_t)s * NH * HLEN);
            acc.x += v.x; acc.y += v.y; acc.z += v.z; acc.w += v.w;
        }
        *(float4*)(out + t4) = acc;
    }
    if (blockIdx.x == 0 && threadIdx.x < NB) {
        const float* xb = x + threadIdx.x * 9;
        float r0 = xb[0] * 10.0f, r1 = xb[1] * 10.0f, r2 = xb[2] * 10.0f;
        float d0 = (xb[3] - xb[6]) * r0;
        float d1 = (xb[4] - xb[7]) * r1;
        float d2 = (xb[5] - xb[8]) * r2;
        float dist = sqrtf(d0 * d0 + d1 * d1 + d2 * d2);
        out[NB * RIR_LEN + threadIdx.x] = 40.0f + SRf * dist / CSOUND;
    }
}

extern "C" void kernel_launch(void* const* d_in, const int* in_sizes, int n_in,
                              void* d_out, int out_size, void* d_ws, size_t ws_size,
                              hipStream_t stream) {
    const float* x = (const float*)d_in[0];
    float* out = (float*)d_out;
    float* ws = (float*)d_ws;  // NB*NSL*NH*HLEN floats = 12.3 MB

    k_paint<<<NB * NSL * NH, BLOCK, 0, stream>>>(x, ws);
    int rblocks = (NB * RIR_LEN / 4 + 255) / 256;  // 188
    k_reduce<<<rblocks, 256, 0, stream>>>(x, ws, out);
}

// Round 16
// 21.874 us; speedup vs baseline: 2.6854x; 1.0993x over previous
//
#include <hip/hip_runtime.h>
#include <math.h>

#define SRf 48000.0f
#define CSOUND 343.0f
#define RIR_LEN 24000
#define TAPS 81
#define HALFT 40
#define NB 8
#define NM 21                 // per-axis entries with order <= 10
#define NTRIP (NM * NM * NM)  // 9261 candidate triples
#define NSL 16                // image-slices per batch
#define NH 2                  // time-halves per slice
#define HLEN (RIR_LEN / NH)   // 12000
#define BLOCK 1024
#define CAPS 256              // per-(slice,half) keeper capacity (worst ~120)

// 0.9^q for q = 0..10
__device__ __constant__ float c_beta[11] = {
    1.0f, 0.9f, 0.81f, 0.729f, 0.6561f, 0.59049f, 0.531441f,
    0.4782969f, 0.43046721f, 0.387420489f, 0.3486784401f};

// Per-axis image table restricted to order <= 10 (pure arithmetic):
//   m in [0,10]:  p=0, n=m-5  -> sign=+1, off=2n, order=2|n|
//   m in [11,20]: p=1, n=m-15 -> sign=-1, off=2n, order=|n-1|+|n|
__device__ __forceinline__ void axis_entry(int m, float& sgn, float& off, int& ord) {
    if (m < 11) {
        int n = m - 5;
        sgn = 1.0f;
        off = 2.0f * (float)n;
        ord = 2 * abs(n);
    } else {
        int n = m - 15;
        sgn = -1.0f;
        off = 2.0f * (float)n;
        ord = abs(n - 1) + abs(n);
    }
}

// f32 -> bf16 (round to nearest even)
__device__ __forceinline__ unsigned bfr(float f) {
    unsigned u = __float_as_uint(f);
    return (u + 0x7FFFu + ((u >> 16) & 1u)) >> 16;
}

// kernel 1: block = (batch, slice, half) with b = blockIdx%8 so every block of
// batch b lands on XCD b (round-robin dispatch) -> its ws partials stay in that
// XCD's L2 for the reduce. Paint windowed-sinc taps into a 48 KB LDS half-RIR,
// write out as bf16 (values <=~0.5, output threshold 10.12 -> huge headroom).
__global__ __launch_bounds__(BLOCK) void k_paint(const float* __restrict__ x,
                                                 unsigned short* __restrict__ ws) {
    __shared__ __align__(16) float s_tile[HLEN];  // 48 KB private half-RIR
    __shared__ float4 s_e[CAPS];   // {amp, frac, amp*sin(pi*frac)/pi, i0}
    __shared__ float2 s_f[CAPS];   // {cos(pi*frac/41), sin(pi*frac/41)}
    __shared__ float2 s_win[TAPS]; // {cos(pi*(ki-40)/41), sin(pi*(ki-40)/41)}
    __shared__ int s_cnt;

    const float PIF = 3.14159265358979323846f;
    const int b = blockIdx.x & 7;           // XCD-aligned batch
    const int rest = blockIdx.x >> 3;       // 0..31
    const int sl = rest >> 1;
    const int h = rest & 1;
    const int H0 = h * HLEN;
    const int tid = threadIdx.x;

    const float* xb = x + b * 9;
    const float r0 = xb[0] * 10.0f, r1 = xb[1] * 10.0f, r2 = xb[2] * 10.0f;
    const float m0 = xb[3] * r0, m1 = xb[4] * r1, m2 = xb[5] * r2;
    const float s0 = xb[6] * r0, s1 = xb[7] * r1, s2 = xb[8] * r2;

    if (tid == 0) s_cnt = 0;
    if (tid < TAPS - 1) {  // window-angle table for ki = 1..80
        int ki = tid + 1;
        float A = PIF * (1.0f / 41.0f) * (float)(ki - HALFT);
        s_win[ki] = make_float2(__cosf(A), __sinf(A));
    }
    for (int j = tid * 4; j < HLEN; j += BLOCK * 4)
        *(float4*)&s_tile[j] = make_float4(0.f, 0.f, 0.f, 0.f);
    __syncthreads();

    // ---- phase A: register-only scan of residue class (one candidate/thread)
    {
        int r = sl + tid * NSL;
        if (r < NTRIP) {
            int mi = r / (NM * NM);
            int rem = r - mi * (NM * NM);
            int mj = rem / NM;
            int mk = rem - mj * NM;

            float si, oi_; int qi; axis_entry(mi, si, oi_, qi);
            float sj, oj_; int qj; axis_entry(mj, sj, oj_, qj);
            float sk, ok_; int qk; axis_entry(mk, sk, ok_, qk);
            int q = qi + qj + qk;
            if (q <= 10) {
                float dx = si * s0 + oi_ * r0 - m0;
                float dy = sj * s1 + oj_ * r1 - m1;
                float dz = sk * s2 + ok_ * r2 - m2;
                float dist = sqrtf(dx * dx + dy * dy + dz * dz);

                float tau = SRf * dist / CSOUND;
                float i0f = floorf(tau);
                int i0 = (int)i0f;
                // in-range taps: idx in [i0+41, i0+120]; intersect [H0, H0+HLEN)?
                if (i0 + HALFT + TAPS - 1 >= H0 && i0 + HALFT + 1 < H0 + HLEN) {
                    float fr = tau - i0f;
                    float amp = c_beta[q] / (4.0f * PIF * dist);
                    int slot = atomicAdd(&s_cnt, 1);
                    float4 e;
                    e.x = amp;
                    e.y = fr;
                    e.z = amp * __sinf(PIF * fr) * (1.0f / PIF);
                    e.w = __int_as_float(i0);
                    s_e[slot] = e;
                    float B = PIF * (1.0f / 41.0f) * fr;
                    s_f[slot] = make_float2(__cosf(B), __sinf(B));
                }
            }
        }
    }
    __syncthreads();

    // ---- phase B: flattened (image, tap) paint. Tap ki=0 contributes 0.
    // win = 0.5*(1+cos(A-B)) = 0.5*(1 + cA*cB + sA*sB): table + 2 fma, no cosf.
    const int n = s_cnt;
    const int total = n * (TAPS - 1);
    for (int w = tid; w < total; w += BLOCK) {
        int img = w / (TAPS - 1);
        int ki = w - img * (TAPS - 1) + 1;  // 1..80
        float4 e = s_e[img];
        int idx = __float_as_int(e.w) + HALFT + ki - H0;
        if (idx < 0 || idx >= HLEN) continue;

        float2 f2 = s_f[img];
        float2 wn = s_win[ki];
        float win = 0.5f * (1.0f + wn.x * f2.x + wn.y * f2.y);
        float tt = (float)(ki - HALFT) - e.y;  // in (-40, 40]
        float v = ((ki & 1) ? e.z : -e.z) * __builtin_amdgcn_rcpf(tt);
        v = (tt == 0.0f) ? e.x : v;  // exact-integer delay
        atomicAdd(&s_tile[idx], v * win);
    }
    __syncthreads();

    // ---- phase C: bf16 writeout (8 values / 16B store per thread-iter)
    unsigned short* wb = ws + (size_t)((b * NSL + sl) * NH + h) * HLEN;
    for (int j = tid * 8; j < HLEN; j += BLOCK * 8) {
        float4 a = *(const float4*)&s_tile[j];
        float4 c = *(const float4*)&s_tile[j + 4];
        uint4 p;
        p.x = bfr(a.x) | (bfr(a.y) << 16);
        p.y = bfr(a.z) | (bfr(a.w) << 16);
        p.z = bfr(c.x) | (bfr(c.y) << 16);
        p.w = bfr(c.z) | (bfr(c.w) << 16);
        *(uint4*)&wb[j] = p;
    }
}

// kernel 2: b = blockIdx%8 (same XCD as the producers -> L2-local reads).
// 192 blocks = 8 batches x 24 segments of 1000 samples.
__global__ __launch_bounds__(256) void k_reduce(const float* __restrict__ x,
                                                const unsigned short* __restrict__ ws,
                                                float* __restrict__ out) {
    const int b = blockIdx.x & 7;
    const int seg = blockIdx.x >> 3;  // 0..23
    const int tid = threadIdx.x;
    int j = seg * 1000 + tid * 4;
    if (tid < 250) {
        int h = j / HLEN;
        int jh = j - h * HLEN;
        const unsigned short* base = ws + (size_t)(b * NSL * NH + h) * HLEN + jh;
        float4 acc = make_float4(0.f, 0.f, 0.f, 0.f);
        #pragma unroll
        for (int s = 0; s < NSL; ++s) {
            ushort4 v = *(const ushort4*)(base + (size_t)s * NH * HLEN);
            acc.x += __uint_as_float((unsigned)v.x << 16);
            acc.y += __uint_as_float((unsigned)v.y << 16);
            acc.z += __uint_as_float((unsigned)v.z << 16);
            acc.w += __uint_as_float((unsigned)v.w << 16);
        }
        *(float4*)(out + (size_t)b * RIR_LEN + j) = acc;
    }
    if (blockIdx.x == 0 && tid < NB) {
        const float* xb = x + tid * 9;
        float r0 = xb[0] * 10.0f, r1 = xb[1] * 10.0f, r2 = xb[2] * 10.0f;
        float d0 = (xb[3] - xb[6]) * r0;
        float d1 = (xb[4] - xb[7]) * r1;
        float d2 = (xb[5] - xb[8]) * r2;
        float dist = sqrtf(d0 * d0 + d1 * d1 + d2 * d2);
        out[NB * RIR_LEN + tid] = 40.0f + SRf * dist / CSOUND;
    }
}

extern "C" void kernel_launch(void* const* d_in, const int* in_sizes, int n_in,
                              void* d_out, int out_size, void* d_ws, size_t ws_size,
                              hipStream_t stream) {
    const float* x = (const float*)d_in[0];
    float* out = (float*)d_out;
    unsigned short* ws = (unsigned short*)d_ws;  // 256*12000 bf16 = 6.14 MB

    k_paint<<<NB * NSL * NH, BLOCK, 0, stream>>>(x, ws);
    k_reduce<<<NB * 24, 256, 0, stream>>>(x, ws, out);
}